// Round 5
// baseline (382.413 us; speedup 1.0000x reference)
//
#include <hip/hip_runtime.h>

// SelfAttention: x(4,2048,1024) fp32; Linear y = x @ W^T + b for Q,K,V;
// S = QK^T/32; P = softmax(S); O = P V; out = O @ Wo^T + bo.
// bf16 MFMA (16x16x32) m97-style gemm_bt, XOR-swizzled LDS (0 conflicts).
// R5: ALL staged operands at ld=1024 (2KB row stride). Evidence: staging-burst
//     locality is monotone in operand stride (R2 2KB:58us, R3 4KB:66us,
//     R4 4.16KB:77us per S-GEMM). Q/K separate buffers (split-C epilogue on
//     the fused QK projection), VT split into two 1024-wide halves, P split
//     into two halves by softmax, PV = dual-K-segment GEMM over the halves.
// Workspace (104MB + 8KB):
//   [0,16M)    xb bf16 [8192][1024] -> later O
//   [16M,20M)  wqkb [2048][1024]   [20M,22M) wvb   [22M,24M) wob
//   [24M,40M)  Q [8192][1024] -> later P0
//   [40M,56M)  K [8192][1024] -> later P1
//   [56M,64M)  VT0 [4][1024][1024]   [64M,72M) VT1 [4][1024][1024]
//   [72M,104M) S bf16 [4][2048][2048]
//   [104M,+8K) bqk fp32 [2048]

typedef __bf16 bf16x8 __attribute__((ext_vector_type(8)));
typedef float f32x4 __attribute__((ext_vector_type(4)));
typedef unsigned short ushort8 __attribute__((ext_vector_type(8)));

__device__ __forceinline__ unsigned short f32_to_bf16(float f) {
  unsigned int u = __float_as_uint(f);
  u += 0x7fffu + ((u >> 16) & 1u);   // round-to-nearest-even
  return (unsigned short)(u >> 16);
}

__device__ __forceinline__ float bf16_to_f32(unsigned short u) {
  return __uint_as_float((unsigned int)u << 16);
}

__device__ __forceinline__ void load_lds16(const void* g, void* l) {
  __builtin_amdgcn_global_load_lds(
      (const __attribute__((address_space(1))) void*)g,
      (__attribute__((address_space(3))) void*)l, 16, 0, 0);
}

// ------------------------------------------------------------- cast kernels
__global__ __launch_bounds__(256) void cast_f32_bf16(
    const float4* __restrict__ in, ushort4* __restrict__ out, int n4) {
  int i = blockIdx.x * 256 + threadIdx.x;
  if (i < n4) {
    float4 f = in[i];
    ushort4 u;
    u.x = f32_to_bf16(f.x);
    u.y = f32_to_bf16(f.y);
    u.z = f32_to_bf16(f.z);
    u.w = f32_to_bf16(f.w);
    out[i] = u;
  }
}

__global__ __launch_bounds__(256) void cast_weights(
    const float4* __restrict__ wq, const float4* __restrict__ wk,
    const float4* __restrict__ wv, const float4* __restrict__ wo,
    ushort4* __restrict__ wqkb, ushort4* __restrict__ wvb,
    ushort4* __restrict__ wob) {
  const int b = blockIdx.x;
  const int seg = b >> 10;                          // 0..3
  const int idx = ((b & 1023) << 8) + threadIdx.x;  // 0..262143 float4s
  const float4* src = seg == 0 ? wq : seg == 1 ? wk : seg == 2 ? wv : wo;
  ushort4* dst = seg == 0 ? wqkb
               : seg == 1 ? (wqkb + 262144)
               : seg == 2 ? wvb : wob;
  float4 f = src[idx];
  ushort4 u;
  u.x = f32_to_bf16(f.x);
  u.y = f32_to_bf16(f.y);
  u.z = f32_to_bf16(f.z);
  u.w = f32_to_bf16(f.w);
  dst[idx] = u;
}

__global__ __launch_bounds__(256) void concat_bias(
    const float* __restrict__ bq, const float* __restrict__ bk,
    float* __restrict__ bqk) {
  int i = blockIdx.x * 256 + threadIdx.x;  // grid 8 -> 2048
  bqk[i] = (i < 1024) ? bq[i] : bk[i - 1024];
}

// ------------------------------------------------------------ gemm (B^T form)
// C[b][M][N] = alpha * (A|A2)[b][M][K] * (B|B2)[b][N][K]^T + bias
// K-segments: k < Kseg reads A/B, k >= Kseg reads A2/B2 at (k-Kseg).
// N-split C: col < Nsplit -> C at col, else C2 at col-Nsplit (per-block uniform;
// Nsplit must be a multiple of 128). bias_mode: 0 none, 1 bias[col], 2 bias[row].
// Tile 128x128, BK=64, 4 waves 2x2, 4x4 16x16x32 MFMA acc per wave.
// LDS: physical 16B chunk p of row r holds logical chunk p^(r&7) (no conflicts).
__global__ __launch_bounds__(256) void gemm_bt(
    const unsigned short* __restrict__ A, const unsigned short* __restrict__ A2,
    const unsigned short* __restrict__ B, const unsigned short* __restrict__ B2,
    void* __restrict__ C, void* __restrict__ C2,
    const float* __restrict__ bias,
    int M, int N, int K, int Kseg, int Nsplit,
    int ldA, int ldB, int ldC,
    float alpha, int out_bf16, int bias_mode,
    long long sA, long long sB, long long sC) {
  __shared__ unsigned short As[128 * 64];
  __shared__ unsigned short Bs[128 * 64];

  const int bz = blockIdx.z;
  const int bm = blockIdx.y, bn = blockIdx.x;
  const int tid = threadIdx.x;
  const int lane = tid & 63, wave = tid >> 6;
  const int wr = wave >> 1, wc = wave & 1;
  const int l16 = lane & 15, quad = lane >> 4;

  f32x4 acc[4][4] = {};

  // staging: thread t covers row (t>>3)+32r; LDS physical chunk (t&7) gets
  // logical chunk (t&7)^(row&7).
  const int srow = tid >> 3;
  const int xr = srow & 7;
  const int scol = ((tid & 7) ^ xr) * 8;
  const long long aoff = (long long)bz * sA + (long long)(bm * 128 + srow) * ldA + scol;
  const long long boff = (long long)bz * sB + (long long)(bn * 128 + srow) * ldB + scol;
  const unsigned short* gA = A + aoff;
  const unsigned short* gA2 = A2 + aoff;
  const unsigned short* gB = B + boff;
  const unsigned short* gB2 = B2 + boff;
  char* ldsA = (char*)As + wave * 1024;  // wave-uniform base; HW adds lane*16
  char* ldsB = (char*)Bs + wave * 1024;

  for (int k0 = 0; k0 < K; k0 += 64) {
    const unsigned short* Ab;
    const unsigned short* Bb;
    int ko;
    if (k0 < Kseg) { Ab = gA; Bb = gB; ko = k0; }
    else           { Ab = gA2; Bb = gB2; ko = k0 - Kseg; }
#pragma unroll
    for (int r = 0; r < 4; r++)
      load_lds16(Ab + ko + (long long)r * 32 * ldA, ldsA + r * 4096);
#pragma unroll
    for (int r = 0; r < 4; r++)
      load_lds16(Bb + ko + (long long)r * 32 * ldB, ldsB + r * 4096);
    __syncthreads();  // drains vmcnt: LDS tiles ready

    const int swz = l16 & 7;
#pragma unroll
    for (int kk = 0; kk < 64; kk += 32) {
      bf16x8 af[4], bf[4];
      const int lc = (kk >> 3) + quad;   // logical chunk 0..7
      const int pco = (lc ^ swz) * 8;    // physical chunk offset, elems
#pragma unroll
      for (int mi = 0; mi < 4; mi++)
        af[mi] = *(const bf16x8*)(As + (wr * 64 + mi * 16 + l16) * 64 + pco);
#pragma unroll
      for (int ni = 0; ni < 4; ni++)
        bf[ni] = *(const bf16x8*)(Bs + (wc * 64 + ni * 16 + l16) * 64 + pco);
#pragma unroll
      for (int mi = 0; mi < 4; mi++)
#pragma unroll
        for (int ni = 0; ni < 4; ni++)
          acc[mi][ni] = __builtin_amdgcn_mfma_f32_16x16x32_bf16(
              af[mi], bf[ni], acc[mi][ni], 0, 0, 0);
    }
    __syncthreads();  // protect LDS before next stage overwrites
  }

  // epilogue: D element (row = quad*4+reg, col = l16) per 16x16 tile
  const int orow0 = bm * 128 + wr * 64 + quad * 4;
  const int ocol0 = bn * 128 + wc * 64 + l16;
  if (out_bf16) {
    unsigned short* Cp = (unsigned short*)C + (long long)bz * sC;
    unsigned short* C2p = (unsigned short*)C2 + (long long)bz * sC;
#pragma unroll
    for (int mi = 0; mi < 4; mi++)
#pragma unroll
      for (int ni = 0; ni < 4; ni++) {
        const int col = ocol0 + ni * 16;
        unsigned short* dst = (col < Nsplit) ? Cp : C2p;
        const int cc = (col < Nsplit) ? col : col - Nsplit;
        const float cb = (bias_mode == 1) ? bias[col] : 0.f;
#pragma unroll
        for (int r = 0; r < 4; r++) {
          const int row = orow0 + mi * 16 + r;
          const float bv = (bias_mode == 2) ? bias[row] : cb;
          const float o = acc[mi][ni][r] * alpha + bv;
          dst[(long long)row * ldC + cc] = f32_to_bf16(o);
        }
      }
  } else {
    float* Cp = (float*)C + (long long)bz * sC;
    float* C2p = (float*)C2 + (long long)bz * sC;
#pragma unroll
    for (int mi = 0; mi < 4; mi++)
#pragma unroll
      for (int ni = 0; ni < 4; ni++) {
        const int col = ocol0 + ni * 16;
        float* dst = (col < Nsplit) ? Cp : C2p;
        const int cc = (col < Nsplit) ? col : col - Nsplit;
        const float cb = (bias_mode == 1) ? bias[col] : 0.f;
#pragma unroll
        for (int r = 0; r < 4; r++) {
          const int row = orow0 + mi * 16 + r;
          const float bv = (bias_mode == 2) ? bias[row] : cb;
          const float o = acc[mi][ni][r] * alpha + bv;
          dst[(long long)row * ldC + cc] = o;
        }
      }
  }
}

// --------------------------------------------- row softmax, bf16, split out
// S: [8192][2048] bf16 -> P0/P1: [8192][1024] halves. One block per row.
__global__ __launch_bounds__(256) void softmax_split(
    const unsigned short* __restrict__ S, unsigned short* __restrict__ P0,
    unsigned short* __restrict__ P1) {
  const long long row = blockIdx.x;
  const unsigned short* s = S + row * 2048;
  const int t = threadIdx.x;
  ushort8 u = *(const ushort8*)(s + t * 8);
  float v[8];
  float mx = -3.4e38f;
#pragma unroll
  for (int i = 0; i < 8; i++) {
    v[i] = bf16_to_f32(u[i]);
    mx = fmaxf(mx, v[i]);
  }
#pragma unroll
  for (int o = 32; o >= 1; o >>= 1) mx = fmaxf(mx, __shfl_xor(mx, o));
  __shared__ float red[4], red2[4];
  if ((t & 63) == 0) red[t >> 6] = mx;
  __syncthreads();
  mx = fmaxf(fmaxf(red[0], red[1]), fmaxf(red[2], red[3]));
  float sum = 0.f;
#pragma unroll
  for (int i = 0; i < 8; i++) {
    v[i] = __expf(v[i] - mx);
    sum += v[i];
  }
#pragma unroll
  for (int o = 32; o >= 1; o >>= 1) sum += __shfl_xor(sum, o);
  if ((t & 63) == 0) red2[t >> 6] = sum;
  __syncthreads();
  sum = red2[0] + red2[1] + red2[2] + red2[3];
  const float inv = 1.0f / sum;
  ushort8 w;
#pragma unroll
  for (int i = 0; i < 8; i++) w[i] = f32_to_bf16(v[i] * inv);
  unsigned short* dst =
      (t < 128) ? (P0 + row * 1024 + t * 8) : (P1 + row * 1024 + (t - 128) * 8);
  *(ushort8*)dst = w;
}

// ----------------------------------------------------------------- launcher
extern "C" void kernel_launch(void* const* d_in, const int* in_sizes, int n_in,
                              void* d_out, int out_size, void* d_ws,
                              size_t ws_size, hipStream_t stream) {
  const float* x = (const float*)d_in[0];
  const float* wq = (const float*)d_in[1];
  const float* bq = (const float*)d_in[2];
  const float* wk = (const float*)d_in[3];
  const float* bk = (const float*)d_in[4];
  const float* wv = (const float*)d_in[5];
  const float* bv = (const float*)d_in[6];
  const float* wo = (const float*)d_in[7];
  const float* bo = (const float*)d_in[8];
  float* out = (float*)d_out;
  char* ws = (char*)d_ws;
  const size_t MB = 1ull << 20;

  unsigned short* xb   = (unsigned short*)(ws + 0);        // later O
  unsigned short* wqkb = (unsigned short*)(ws + 16 * MB);
  unsigned short* wvb  = (unsigned short*)(ws + 20 * MB);
  unsigned short* wob  = (unsigned short*)(ws + 22 * MB);
  unsigned short* Q    = (unsigned short*)(ws + 24 * MB);  // later P0
  unsigned short* Kb   = (unsigned short*)(ws + 40 * MB);  // later P1
  unsigned short* VT0  = (unsigned short*)(ws + 56 * MB);
  unsigned short* VT1  = (unsigned short*)(ws + 64 * MB);
  unsigned short* S    = (unsigned short*)(ws + 72 * MB);
  float*          bqk  = (float*)(ws + 104 * MB);
  unsigned short* P0 = Q, *P1 = Kb, *O = xb;

  // 1) casts
  cast_f32_bf16<<<dim3(8192), dim3(256), 0, stream>>>((const float4*)x,
                                                      (ushort4*)xb, 2097152);
  cast_weights<<<dim3(4096), dim3(256), 0, stream>>>(
      (const float4*)wq, (const float4*)wk, (const float4*)wv,
      (const float4*)wo, (ushort4*)wqkb, (ushort4*)wvb, (ushort4*)wob);
  concat_bias<<<dim3(8), dim3(256), 0, stream>>>(bq, bk, bqk);

  // 2) fused Q+K projection, split C -> Q and K buffers (ld 1024)
  gemm_bt<<<dim3(16, 64, 1), dim3(256), 0, stream>>>(
      xb, xb, wqkb, wqkb, Q, Kb, bqk, 8192, 2048, 1024, 1024, 1024, 1024, 1024,
      1024, 1.f, 1, 1, 0, 0, 0);

  // 3) VT halves: VT0[b][d][s<1024], VT1[b][d][s>=1024]; bias per-row (bv[d])
  gemm_bt<<<dim3(8, 8, 4), dim3(256), 0, stream>>>(
      wvb, wvb, xb, xb, VT0, VT0, bv, 1024, 1024, 1024, 1024, 1024, 1024, 1024,
      1024, 1.f, 1, 2, 0, 2048ll * 1024, 1024ll * 1024);
  gemm_bt<<<dim3(8, 8, 4), dim3(256), 0, stream>>>(
      wvb, wvb, xb + 1024 * 1024, xb + 1024 * 1024, VT1, VT1, bv, 1024, 1024,
      1024, 1024, 1024, 1024, 1024, 1024, 1.f, 1, 2, 0, 2048ll * 1024,
      1024ll * 1024);

  // 4) S = Q K^T / 32 (bf16 out, fp32 accum), batched over 4
  gemm_bt<<<dim3(16, 16, 4), dim3(256), 0, stream>>>(
      Q, Q, Kb, Kb, S, S, nullptr, 2048, 2048, 1024, 1024, 2048, 1024, 1024,
      2048, 0.03125f, 1, 0, 2048ll * 1024, 2048ll * 1024, 2048ll * 2048);

  // 5) P = softmax rows of S, split into P0/P1 (over Q/K buffers)
  softmax_split<<<dim3(8192), dim3(256), 0, stream>>>(S, P0, P1);

  // 6) O = P0 VT0^T + P1 VT1^T (dual K-segment), bf16, over xb
  gemm_bt<<<dim3(8, 16, 4), dim3(256), 0, stream>>>(
      P0, P1, VT0, VT1, O, O, nullptr, 2048, 1024, 2048, 1024, 1024, 1024,
      1024, 1024, 1.f, 1, 0, 2048ll * 1024, 1024ll * 1024, 2048ll * 1024);

  // 7) out = O @ Wo^T + bo, fp32 to d_out
  gemm_bt<<<dim3(8, 64, 1), dim3(256), 0, stream>>>(
      O, O, wob, wob, out, out, bo, 8192, 1024, 1024, 1024, 1024, 1024, 1024,
      1024, 1.f, 0, 1, 0, 0, 0);
}

// Round 6
// 347.277 us; speedup vs baseline: 1.1012x; 1.1012x over previous
//
#include <hip/hip_runtime.h>

// SelfAttention: x(4,2048,1024) fp32; Linear y = x @ W^T + b for Q,K,V;
// S = QK^T/32; P = softmax(S); O = P V; out = O @ Wo^T + bo.
// bf16 MFMA (16x16x32) m97-style gemm_bt, XOR-swizzled LDS (0 conflicts).
// R6: revert S to fp32 C (evidence: S-GEMM 58us w/ fp32 C in R2 vs 66-68us
//     w/ bf16 C in R3/R5, independent of operand stride). Collapse pipeline
//     to 7 dispatches: megacast, fused QK-proj (split C), VT via gemm z=8,
//     S-GEMM (fp32), softmax-split, PV (dual K-seg), out-proj.
// All staged operands at ld=1024 (2KB stride).
// Workspace (136MB):
//   [0,16M)    xb bf16 [8192][1024] -> later O
//   [16M,20M)  wqkb [2048][1024] (wq rows 0-1023, wk 1024-2047)
//   [20M,22M)  wvb   [22M,24M) wob
//   [24M,40M)  Q [8192][1024] -> later P0
//   [40M,56M)  K [8192][1024] -> later P1
//   [56M,72M)  VT [8][1024][1024] z-interleaved: z=2*batch+half, half=s/1024
//   [72M,136M) S fp32 [4][2048][2048]; first 8KB doubles as bqk (dead by then)

typedef __bf16 bf16x8 __attribute__((ext_vector_type(8)));
typedef float f32x4 __attribute__((ext_vector_type(4)));
typedef unsigned short ushort8 __attribute__((ext_vector_type(8)));

__device__ __forceinline__ unsigned short f32_to_bf16(float f) {
  unsigned int u = __float_as_uint(f);
  u += 0x7fffu + ((u >> 16) & 1u);   // round-to-nearest-even
  return (unsigned short)(u >> 16);
}

__device__ __forceinline__ void load_lds16(const void* g, void* l) {
  __builtin_amdgcn_global_load_lds(
      (const __attribute__((address_space(1))) void*)g,
      (__attribute__((address_space(3))) void*)l, 16, 0, 0);
}

// ------------------------------------------------------------ megacast
// blocks [0,8192): x -> xb; [8192,12288): weights; block 12288: bias concat.
__global__ __launch_bounds__(256) void megacast(
    const float4* __restrict__ x, const float4* __restrict__ wq,
    const float4* __restrict__ wk, const float4* __restrict__ wv,
    const float4* __restrict__ wo, const float* __restrict__ bq,
    const float* __restrict__ bk, ushort4* __restrict__ xb,
    ushort4* __restrict__ wqkb, ushort4* __restrict__ wvb,
    ushort4* __restrict__ wob, float* __restrict__ bqk) {
  const int b = blockIdx.x;
  const int t = threadIdx.x;
  if (b < 8192) {
    const int i = b * 256 + t;
    float4 f = x[i];
    ushort4 u;
    u.x = f32_to_bf16(f.x); u.y = f32_to_bf16(f.y);
    u.z = f32_to_bf16(f.z); u.w = f32_to_bf16(f.w);
    xb[i] = u;
  } else if (b < 12288) {
    const int bb = b - 8192;
    const int seg = bb >> 10;                       // 0..3
    const int idx = ((bb & 1023) << 8) + t;         // 0..262143
    const float4* src = seg == 0 ? wq : seg == 1 ? wk : seg == 2 ? wv : wo;
    ushort4* dst = seg == 0 ? wqkb
                 : seg == 1 ? (wqkb + 262144)
                 : seg == 2 ? wvb : wob;
    float4 f = src[idx];
    ushort4 u;
    u.x = f32_to_bf16(f.x); u.y = f32_to_bf16(f.y);
    u.z = f32_to_bf16(f.z); u.w = f32_to_bf16(f.w);
    dst[idx] = u;
  } else {
#pragma unroll
    for (int i = 0; i < 8; i++) {
      const int j = t + i * 256;  // 0..2047
      bqk[j] = (j < 1024) ? bq[j] : bk[j - 1024];
    }
  }
}

// ------------------------------------------------------------ gemm (B^T form)
// C[b][M][N] = alpha * (A|A2)[b][M][K] * (B|B2)[b][N][K]^T + bias
// K-segments: k < Kseg reads A/B, else A2/B2 at (k-Kseg).
// N-split C: col < Nsplit -> C, else C2 at col-Nsplit (Nsplit multiple of 128).
// bias_mode: 0 none, 1 bias[col], 2 bias[row].
// Tile 128x128, BK=64, 4 waves 2x2, 4x4 16x16x32 MFMA acc per wave.
// LDS: physical 16B chunk p of row r holds logical chunk p^(r&7) (0 conflicts).
__global__ __launch_bounds__(256) void gemm_bt(
    const unsigned short* __restrict__ A, const unsigned short* __restrict__ A2,
    const unsigned short* __restrict__ B, const unsigned short* __restrict__ B2,
    void* __restrict__ C, void* __restrict__ C2,
    const float* __restrict__ bias,
    int M, int N, int K, int Kseg, int Nsplit,
    int ldA, int ldB, int ldC,
    float alpha, int out_bf16, int bias_mode,
    long long sA, long long sB, long long sC) {
  __shared__ unsigned short As[128 * 64];
  __shared__ unsigned short Bs[128 * 64];

  const int bz = blockIdx.z;
  const int bm = blockIdx.y, bn = blockIdx.x;
  const int tid = threadIdx.x;
  const int lane = tid & 63, wave = tid >> 6;
  const int wr = wave >> 1, wc = wave & 1;
  const int l16 = lane & 15, quad = lane >> 4;

  f32x4 acc[4][4] = {};

  // staging: thread t covers row (t>>3)+32r; LDS physical chunk (t&7) gets
  // logical chunk (t&7)^(row&7).
  const int srow = tid >> 3;
  const int xr = srow & 7;
  const int scol = ((tid & 7) ^ xr) * 8;
  const long long aoff =
      (long long)bz * sA + (long long)(bm * 128 + srow) * ldA + scol;
  const long long boff =
      (long long)bz * sB + (long long)(bn * 128 + srow) * ldB + scol;
  const unsigned short* gA = A + aoff;
  const unsigned short* gA2 = A2 + aoff;
  const unsigned short* gB = B + boff;
  const unsigned short* gB2 = B2 + boff;
  char* ldsA = (char*)As + wave * 1024;  // wave-uniform base; HW adds lane*16
  char* ldsB = (char*)Bs + wave * 1024;

  for (int k0 = 0; k0 < K; k0 += 64) {
    const unsigned short* Ab;
    const unsigned short* Bb;
    int ko;
    if (k0 < Kseg) { Ab = gA; Bb = gB; ko = k0; }
    else           { Ab = gA2; Bb = gB2; ko = k0 - Kseg; }
#pragma unroll
    for (int r = 0; r < 4; r++)
      load_lds16(Ab + ko + (long long)r * 32 * ldA, ldsA + r * 4096);
#pragma unroll
    for (int r = 0; r < 4; r++)
      load_lds16(Bb + ko + (long long)r * 32 * ldB, ldsB + r * 4096);
    __syncthreads();  // drains vmcnt: LDS tiles ready

    const int swz = l16 & 7;
#pragma unroll
    for (int kk = 0; kk < 64; kk += 32) {
      bf16x8 af[4], bf[4];
      const int lc = (kk >> 3) + quad;   // logical chunk 0..7
      const int pco = (lc ^ swz) * 8;    // physical chunk offset, elems
#pragma unroll
      for (int mi = 0; mi < 4; mi++)
        af[mi] = *(const bf16x8*)(As + (wr * 64 + mi * 16 + l16) * 64 + pco);
#pragma unroll
      for (int ni = 0; ni < 4; ni++)
        bf[ni] = *(const bf16x8*)(Bs + (wc * 64 + ni * 16 + l16) * 64 + pco);
#pragma unroll
      for (int mi = 0; mi < 4; mi++)
#pragma unroll
        for (int ni = 0; ni < 4; ni++)
          acc[mi][ni] = __builtin_amdgcn_mfma_f32_16x16x32_bf16(
              af[mi], bf[ni], acc[mi][ni], 0, 0, 0);
    }
    __syncthreads();  // protect LDS before next stage overwrites
  }

  // epilogue: D element (row = quad*4+reg, col = l16) per 16x16 tile
  const int orow0 = bm * 128 + wr * 64 + quad * 4;
  const int ocol0 = bn * 128 + wc * 64 + l16;
  if (out_bf16) {
    unsigned short* Cp = (unsigned short*)C + (long long)bz * sC;
    unsigned short* C2p = (unsigned short*)C2 + (long long)bz * sC;
#pragma unroll
    for (int mi = 0; mi < 4; mi++)
#pragma unroll
      for (int ni = 0; ni < 4; ni++) {
        const int col = ocol0 + ni * 16;
        unsigned short* dst = (col < Nsplit) ? Cp : C2p;
        const int cc = (col < Nsplit) ? col : col - Nsplit;
        const float cb = (bias_mode == 1) ? bias[col] : 0.f;
#pragma unroll
        for (int r = 0; r < 4; r++) {
          const int row = orow0 + mi * 16 + r;
          const float bv = (bias_mode == 2) ? bias[row] : cb;
          const float o = acc[mi][ni][r] * alpha + bv;
          dst[(long long)row * ldC + cc] = f32_to_bf16(o);
        }
      }
  } else {
    float* Cp = (float*)C + (long long)bz * sC;
    float* C2p = (float*)C2 + (long long)bz * sC;
#pragma unroll
    for (int mi = 0; mi < 4; mi++)
#pragma unroll
      for (int ni = 0; ni < 4; ni++) {
        const int col = ocol0 + ni * 16;
        float* dst = (col < Nsplit) ? Cp : C2p;
        const int cc = (col < Nsplit) ? col : col - Nsplit;
        const float cb = (bias_mode == 1) ? bias[col] : 0.f;
#pragma unroll
        for (int r = 0; r < 4; r++) {
          const int row = orow0 + mi * 16 + r;
          const float bv = (bias_mode == 2) ? bias[row] : cb;
          const float o = acc[mi][ni][r] * alpha + bv;
          dst[(long long)row * ldC + cc] = o;
        }
      }
  }
}

// --------------------------------------- row softmax fp32 -> bf16 split out
// S: [8192][2048] fp32 -> P0/P1: [8192][1024] bf16 halves. One block per row.
__global__ __launch_bounds__(256) void softmax_split(
    const float* __restrict__ S, unsigned short* __restrict__ P0,
    unsigned short* __restrict__ P1) {
  const long long row = blockIdx.x;
  const float* s = S + row * 2048;
  const int t = threadIdx.x;
  float4 a = ((const float4*)s)[t * 2];
  float4 b = ((const float4*)s)[t * 2 + 1];
  float v[8] = {a.x, a.y, a.z, a.w, b.x, b.y, b.z, b.w};
  float mx = -3.4e38f;
#pragma unroll
  for (int i = 0; i < 8; i++) mx = fmaxf(mx, v[i]);
#pragma unroll
  for (int o = 32; o >= 1; o >>= 1) mx = fmaxf(mx, __shfl_xor(mx, o));
  __shared__ float red[4], red2[4];
  if ((t & 63) == 0) red[t >> 6] = mx;
  __syncthreads();
  mx = fmaxf(fmaxf(red[0], red[1]), fmaxf(red[2], red[3]));
  float sum = 0.f;
#pragma unroll
  for (int i = 0; i < 8; i++) {
    v[i] = __expf(v[i] - mx);
    sum += v[i];
  }
#pragma unroll
  for (int o = 32; o >= 1; o >>= 1) sum += __shfl_xor(sum, o);
  if ((t & 63) == 0) red2[t >> 6] = sum;
  __syncthreads();
  sum = red2[0] + red2[1] + red2[2] + red2[3];
  const float inv = 1.0f / sum;
  ushort8 w;
#pragma unroll
  for (int i = 0; i < 8; i++) w[i] = f32_to_bf16(v[i] * inv);
  unsigned short* dst =
      (t < 128) ? (P0 + row * 1024 + t * 8) : (P1 + row * 1024 + (t - 128) * 8);
  *(ushort8*)dst = w;
}

// ----------------------------------------------------------------- launcher
extern "C" void kernel_launch(void* const* d_in, const int* in_sizes, int n_in,
                              void* d_out, int out_size, void* d_ws,
                              size_t ws_size, hipStream_t stream) {
  const float* x = (const float*)d_in[0];
  const float* wq = (const float*)d_in[1];
  const float* bq = (const float*)d_in[2];
  const float* wk = (const float*)d_in[3];
  const float* bk = (const float*)d_in[4];
  const float* wv = (const float*)d_in[5];
  const float* bv = (const float*)d_in[6];
  const float* wo = (const float*)d_in[7];
  const float* bo = (const float*)d_in[8];
  float* out = (float*)d_out;
  char* ws = (char*)d_ws;
  const size_t MB = 1ull << 20;

  unsigned short* xb   = (unsigned short*)(ws + 0);        // later O
  unsigned short* wqkb = (unsigned short*)(ws + 16 * MB);
  unsigned short* wvb  = (unsigned short*)(ws + 20 * MB);
  unsigned short* wob  = (unsigned short*)(ws + 22 * MB);
  unsigned short* Q    = (unsigned short*)(ws + 24 * MB);  // later P0
  unsigned short* Kb   = (unsigned short*)(ws + 40 * MB);  // later P1
  unsigned short* VT   = (unsigned short*)(ws + 56 * MB);  // [8][1024][1024]
  float*          S    = (float*)(ws + 72 * MB);           // 64MB fp32
  float*          bqk  = (float*)(ws + 72 * MB);           // dead before S write
  unsigned short* P0 = Q, *P1 = Kb, *O = xb;

  // 1) megacast: x, 4 weights, bias concat  (bqk aliases S head; consumed in 2)
  megacast<<<dim3(12289), dim3(256), 0, stream>>>(
      (const float4*)x, (const float4*)wq, (const float4*)wk,
      (const float4*)wv, (const float4*)wo, bq, bk, (ushort4*)xb,
      (ushort4*)wqkb, (ushort4*)wvb, (ushort4*)wob, bqk);

  // 2) fused Q+K projection, split C -> Q and K (ld 1024)
  gemm_bt<<<dim3(16, 64, 1), dim3(256), 0, stream>>>(
      xb, xb, wqkb, wqkb, Q, Kb, bqk, 8192, 2048, 1024, 1024, 1024, 1024, 1024,
      1024, 1.f, 1, 1, 0, 0, 0);

  // 3) VT[z=2b+h][d][s'] = Wv x^T + bv, z in [0,8), one launch
  gemm_bt<<<dim3(8, 8, 8), dim3(256), 0, stream>>>(
      wvb, wvb, xb, xb, VT, VT, bv, 1024, 1024, 1024, 1024, 1024, 1024, 1024,
      1024, 1.f, 1, 2, 0, 1048576ll, 1048576ll);

  // 4) S = Q K^T / 32 (fp32 out), batched over 4
  gemm_bt<<<dim3(16, 16, 4), dim3(256), 0, stream>>>(
      Q, Q, Kb, Kb, S, S, nullptr, 2048, 2048, 1024, 1024, 2048, 1024, 1024,
      2048, 0.03125f, 0, 0, 2048ll * 1024, 2048ll * 1024, 2048ll * 2048);

  // 5) P = softmax rows of S -> P0/P1 (over Q/K buffers)
  softmax_split<<<dim3(8192), dim3(256), 0, stream>>>(S, P0, P1);

  // 6) O = P0 VT0^T + P1 VT1^T (dual K-segment), bf16, over xb
  gemm_bt<<<dim3(8, 16, 4), dim3(256), 0, stream>>>(
      P0, P1, VT, VT + 1048576, O, O, nullptr, 2048, 1024, 2048, 1024, 1024,
      1024, 1024, 1024, 1.f, 1, 0, 2048ll * 1024, 2097152ll, 2048ll * 1024);

  // 7) out = O @ Wo^T + bo, fp32 to d_out
  gemm_bt<<<dim3(8, 64, 1), dim3(256), 0, stream>>>(
      O, O, wob, wob, out, out, bo, 8192, 1024, 1024, 1024, 1024, 1024, 1024,
      1024, 1.f, 0, 1, 0, 0, 0);
}

// Round 7
// 345.579 us; speedup vs baseline: 1.1066x; 1.0049x over previous
//
#include <hip/hip_runtime.h>

// SelfAttention: x(4,2048,1024) fp32; Linear y = x @ W^T + b for Q,K,V;
// S = QK^T/32; P = softmax(S); O = P V; out = O @ Wo^T + bo.
// bf16 MFMA (16x16x32) m97-style gemm_bt, XOR-swizzled LDS (0 conflicts).
// R6: fp32 S, 7 dispatches (megacast, fused QK-proj, VT via gemm z=8,
//     S-GEMM, softmax-split, PV dual-K-seg, out-proj). 347 us.
// R7: XCD-affinity block swizzle in gemm_bt. Evidence: QK-proj reads 20 MB
//     of operands but FETCH=69.7 MB (A-tiles fetched ~4x from HBM; blocks
//     sharing an A-tile scatter round-robin over 8 XCD L2s and L3 thrashes
//     at ~216 MB working set). Map all blocks of one bm to one XCD:
//     lin=by*nbn+bx; bm=(lin&7)+8*((lin>>3)/nbn); bn=(lin>>3)%nbn.
//     Requires gridDim.y % 8 == 0 (true for all 5 GEMM launches).
// Workspace (136MB):
//   [0,16M)    xb bf16 [8192][1024] -> later O
//   [16M,20M)  wqkb [2048][1024] (wq rows 0-1023, wk 1024-2047)
//   [20M,22M)  wvb   [22M,24M) wob
//   [24M,40M)  Q [8192][1024] -> later P0
//   [40M,56M)  K [8192][1024] -> later P1
//   [56M,72M)  VT [8][1024][1024] z-interleaved: z=2*batch+half, half=s/1024
//   [72M,136M) S fp32 [4][2048][2048]; first 8KB doubles as bqk (dead by then)

typedef __bf16 bf16x8 __attribute__((ext_vector_type(8)));
typedef float f32x4 __attribute__((ext_vector_type(4)));
typedef unsigned short ushort8 __attribute__((ext_vector_type(8)));

__device__ __forceinline__ unsigned short f32_to_bf16(float f) {
  unsigned int u = __float_as_uint(f);
  u += 0x7fffu + ((u >> 16) & 1u);   // round-to-nearest-even
  return (unsigned short)(u >> 16);
}

__device__ __forceinline__ void load_lds16(const void* g, void* l) {
  __builtin_amdgcn_global_load_lds(
      (const __attribute__((address_space(1))) void*)g,
      (__attribute__((address_space(3))) void*)l, 16, 0, 0);
}

// ------------------------------------------------------------ megacast
// blocks [0,8192): x -> xb; [8192,12288): weights; block 12288: bias concat.
__global__ __launch_bounds__(256) void megacast(
    const float4* __restrict__ x, const float4* __restrict__ wq,
    const float4* __restrict__ wk, const float4* __restrict__ wv,
    const float4* __restrict__ wo, const float* __restrict__ bq,
    const float* __restrict__ bk, ushort4* __restrict__ xb,
    ushort4* __restrict__ wqkb, ushort4* __restrict__ wvb,
    ushort4* __restrict__ wob, float* __restrict__ bqk) {
  const int b = blockIdx.x;
  const int t = threadIdx.x;
  if (b < 8192) {
    const int i = b * 256 + t;
    float4 f = x[i];
    ushort4 u;
    u.x = f32_to_bf16(f.x); u.y = f32_to_bf16(f.y);
    u.z = f32_to_bf16(f.z); u.w = f32_to_bf16(f.w);
    xb[i] = u;
  } else if (b < 12288) {
    const int bb = b - 8192;
    const int seg = bb >> 10;                       // 0..3
    const int idx = ((bb & 1023) << 8) + t;         // 0..262143
    const float4* src = seg == 0 ? wq : seg == 1 ? wk : seg == 2 ? wv : wo;
    ushort4* dst = seg == 0 ? wqkb
                 : seg == 1 ? (wqkb + 262144)
                 : seg == 2 ? wvb : wob;
    float4 f = src[idx];
    ushort4 u;
    u.x = f32_to_bf16(f.x); u.y = f32_to_bf16(f.y);
    u.z = f32_to_bf16(f.z); u.w = f32_to_bf16(f.w);
    dst[idx] = u;
  } else {
#pragma unroll
    for (int i = 0; i < 8; i++) {
      const int j = t + i * 256;  // 0..2047
      bqk[j] = (j < 1024) ? bq[j] : bk[j - 1024];
    }
  }
}

// ------------------------------------------------------------ gemm (B^T form)
// C[b][M][N] = alpha * (A|A2)[b][M][K] * (B|B2)[b][N][K]^T + bias
// K-segments: k < Kseg reads A/B, else A2/B2 at (k-Kseg).
// N-split C: col < Nsplit -> C, else C2 at col-Nsplit (Nsplit multiple of 128).
// bias_mode: 0 none, 1 bias[col], 2 bias[row].
// Tile 128x128, BK=64, 4 waves 2x2, 4x4 16x16x32 MFMA acc per wave.
// LDS: physical 16B chunk p of row r holds logical chunk p^(r&7) (0 conflicts).
// Block swizzle: all bn-blocks of one bm share an XCD (L2 A-tile residency).
__global__ __launch_bounds__(256) void gemm_bt(
    const unsigned short* __restrict__ A, const unsigned short* __restrict__ A2,
    const unsigned short* __restrict__ B, const unsigned short* __restrict__ B2,
    void* __restrict__ C, void* __restrict__ C2,
    const float* __restrict__ bias,
    int M, int N, int K, int Kseg, int Nsplit,
    int ldA, int ldB, int ldC,
    float alpha, int out_bf16, int bias_mode,
    long long sA, long long sB, long long sC) {
  __shared__ unsigned short As[128 * 64];
  __shared__ unsigned short Bs[128 * 64];

  const int bz = blockIdx.z;
  // XCD-affinity swizzle (gridDim.y % 8 == 0 required):
  const int nbn = gridDim.x;
  const int lin = blockIdx.y * nbn + blockIdx.x;
  const int g = lin >> 3;
  const int bm = (lin & 7) + 8 * (g / nbn);
  const int bn = g % nbn;

  const int tid = threadIdx.x;
  const int lane = tid & 63, wave = tid >> 6;
  const int wr = wave >> 1, wc = wave & 1;
  const int l16 = lane & 15, quad = lane >> 4;

  f32x4 acc[4][4] = {};

  // staging: thread t covers row (t>>3)+32r; LDS physical chunk (t&7) gets
  // logical chunk (t&7)^(row&7).
  const int srow = tid >> 3;
  const int xr = srow & 7;
  const int scol = ((tid & 7) ^ xr) * 8;
  const long long aoff =
      (long long)bz * sA + (long long)(bm * 128 + srow) * ldA + scol;
  const long long boff =
      (long long)bz * sB + (long long)(bn * 128 + srow) * ldB + scol;
  const unsigned short* gA = A + aoff;
  const unsigned short* gA2 = A2 + aoff;
  const unsigned short* gB = B + boff;
  const unsigned short* gB2 = B2 + boff;
  char* ldsA = (char*)As + wave * 1024;  // wave-uniform base; HW adds lane*16
  char* ldsB = (char*)Bs + wave * 1024;

  for (int k0 = 0; k0 < K; k0 += 64) {
    const unsigned short* Ab;
    const unsigned short* Bb;
    int ko;
    if (k0 < Kseg) { Ab = gA; Bb = gB; ko = k0; }
    else           { Ab = gA2; Bb = gB2; ko = k0 - Kseg; }
#pragma unroll
    for (int r = 0; r < 4; r++)
      load_lds16(Ab + ko + (long long)r * 32 * ldA, ldsA + r * 4096);
#pragma unroll
    for (int r = 0; r < 4; r++)
      load_lds16(Bb + ko + (long long)r * 32 * ldB, ldsB + r * 4096);
    __syncthreads();  // drains vmcnt: LDS tiles ready

    const int swz = l16 & 7;
#pragma unroll
    for (int kk = 0; kk < 64; kk += 32) {
      bf16x8 af[4], bf[4];
      const int lc = (kk >> 3) + quad;   // logical chunk 0..7
      const int pco = (lc ^ swz) * 8;    // physical chunk offset, elems
#pragma unroll
      for (int mi = 0; mi < 4; mi++)
        af[mi] = *(const bf16x8*)(As + (wr * 64 + mi * 16 + l16) * 64 + pco);
#pragma unroll
      for (int ni = 0; ni < 4; ni++)
        bf[ni] = *(const bf16x8*)(Bs + (wc * 64 + ni * 16 + l16) * 64 + pco);
#pragma unroll
      for (int mi = 0; mi < 4; mi++)
#pragma unroll
        for (int ni = 0; ni < 4; ni++)
          acc[mi][ni] = __builtin_amdgcn_mfma_f32_16x16x32_bf16(
              af[mi], bf[ni], acc[mi][ni], 0, 0, 0);
    }
    __syncthreads();  // protect LDS before next stage overwrites
  }

  // epilogue: D element (row = quad*4+reg, col = l16) per 16x16 tile
  const int orow0 = bm * 128 + wr * 64 + quad * 4;
  const int ocol0 = bn * 128 + wc * 64 + l16;
  if (out_bf16) {
    unsigned short* Cp = (unsigned short*)C + (long long)bz * sC;
    unsigned short* C2p = (unsigned short*)C2 + (long long)bz * sC;
#pragma unroll
    for (int mi = 0; mi < 4; mi++)
#pragma unroll
      for (int ni = 0; ni < 4; ni++) {
        const int col = ocol0 + ni * 16;
        unsigned short* dst = (col < Nsplit) ? Cp : C2p;
        const int cc = (col < Nsplit) ? col : col - Nsplit;
        const float cb = (bias_mode == 1) ? bias[col] : 0.f;
#pragma unroll
        for (int r = 0; r < 4; r++) {
          const int row = orow0 + mi * 16 + r;
          const float bv = (bias_mode == 2) ? bias[row] : cb;
          const float o = acc[mi][ni][r] * alpha + bv;
          dst[(long long)row * ldC + cc] = f32_to_bf16(o);
        }
      }
  } else {
    float* Cp = (float*)C + (long long)bz * sC;
    float* C2p = (float*)C2 + (long long)bz * sC;
#pragma unroll
    for (int mi = 0; mi < 4; mi++)
#pragma unroll
      for (int ni = 0; ni < 4; ni++) {
        const int col = ocol0 + ni * 16;
        float* dst = (col < Nsplit) ? Cp : C2p;
        const int cc = (col < Nsplit) ? col : col - Nsplit;
        const float cb = (bias_mode == 1) ? bias[col] : 0.f;
#pragma unroll
        for (int r = 0; r < 4; r++) {
          const int row = orow0 + mi * 16 + r;
          const float bv = (bias_mode == 2) ? bias[row] : cb;
          const float o = acc[mi][ni][r] * alpha + bv;
          dst[(long long)row * ldC + cc] = o;
        }
      }
  }
}

// --------------------------------------- row softmax fp32 -> bf16 split out
// S: [8192][2048] fp32 -> P0/P1: [8192][1024] bf16 halves. One block per row.
__global__ __launch_bounds__(256) void softmax_split(
    const float* __restrict__ S, unsigned short* __restrict__ P0,
    unsigned short* __restrict__ P1) {
  const long long row = blockIdx.x;
  const float* s = S + row * 2048;
  const int t = threadIdx.x;
  float4 a = ((const float4*)s)[t * 2];
  float4 b = ((const float4*)s)[t * 2 + 1];
  float v[8] = {a.x, a.y, a.z, a.w, b.x, b.y, b.z, b.w};
  float mx = -3.4e38f;
#pragma unroll
  for (int i = 0; i < 8; i++) mx = fmaxf(mx, v[i]);
#pragma unroll
  for (int o = 32; o >= 1; o >>= 1) mx = fmaxf(mx, __shfl_xor(mx, o));
  __shared__ float red[4], red2[4];
  if ((t & 63) == 0) red[t >> 6] = mx;
  __syncthreads();
  mx = fmaxf(fmaxf(red[0], red[1]), fmaxf(red[2], red[3]));
  float sum = 0.f;
#pragma unroll
  for (int i = 0; i < 8; i++) {
    v[i] = __expf(v[i] - mx);
    sum += v[i];
  }
#pragma unroll
  for (int o = 32; o >= 1; o >>= 1) sum += __shfl_xor(sum, o);
  if ((t & 63) == 0) red2[t >> 6] = sum;
  __syncthreads();
  sum = red2[0] + red2[1] + red2[2] + red2[3];
  const float inv = 1.0f / sum;
  ushort8 w;
#pragma unroll
  for (int i = 0; i < 8; i++) w[i] = f32_to_bf16(v[i] * inv);
  unsigned short* dst =
      (t < 128) ? (P0 + row * 1024 + t * 8) : (P1 + row * 1024 + (t - 128) * 8);
  *(ushort8*)dst = w;
}

// ----------------------------------------------------------------- launcher
extern "C" void kernel_launch(void* const* d_in, const int* in_sizes, int n_in,
                              void* d_out, int out_size, void* d_ws,
                              size_t ws_size, hipStream_t stream) {
  const float* x = (const float*)d_in[0];
  const float* wq = (const float*)d_in[1];
  const float* bq = (const float*)d_in[2];
  const float* wk = (const float*)d_in[3];
  const float* bk = (const float*)d_in[4];
  const float* wv = (const float*)d_in[5];
  const float* bv = (const float*)d_in[6];
  const float* wo = (const float*)d_in[7];
  const float* bo = (const float*)d_in[8];
  float* out = (float*)d_out;
  char* ws = (char*)d_ws;
  const size_t MB = 1ull << 20;

  unsigned short* xb   = (unsigned short*)(ws + 0);        // later O
  unsigned short* wqkb = (unsigned short*)(ws + 16 * MB);
  unsigned short* wvb  = (unsigned short*)(ws + 20 * MB);
  unsigned short* wob  = (unsigned short*)(ws + 22 * MB);
  unsigned short* Q    = (unsigned short*)(ws + 24 * MB);  // later P0
  unsigned short* Kb   = (unsigned short*)(ws + 40 * MB);  // later P1
  unsigned short* VT   = (unsigned short*)(ws + 56 * MB);  // [8][1024][1024]
  float*          S    = (float*)(ws + 72 * MB);           // 64MB fp32
  float*          bqk  = (float*)(ws + 72 * MB);           // dead before S write
  unsigned short* P0 = Q, *P1 = Kb, *O = xb;

  // 1) megacast: x, 4 weights, bias concat  (bqk aliases S head; consumed in 2)
  megacast<<<dim3(12289), dim3(256), 0, stream>>>(
      (const float4*)x, (const float4*)wq, (const float4*)wk,
      (const float4*)wv, (const float4*)wo, bq, bk, (ushort4*)xb,
      (ushort4*)wqkb, (ushort4*)wvb, (ushort4*)wob, bqk);

  // 2) fused Q+K projection, split C -> Q and K (ld 1024)
  gemm_bt<<<dim3(16, 64, 1), dim3(256), 0, stream>>>(
      xb, xb, wqkb, wqkb, Q, Kb, bqk, 8192, 2048, 1024, 1024, 1024, 1024, 1024,
      1024, 1.f, 1, 1, 0, 0, 0);

  // 3) VT[z=2b+h][d][s'] = Wv x^T + bv, z in [0,8), one launch
  gemm_bt<<<dim3(8, 8, 8), dim3(256), 0, stream>>>(
      wvb, wvb, xb, xb, VT, VT, bv, 1024, 1024, 1024, 1024, 1024, 1024, 1024,
      1024, 1.f, 1, 2, 0, 1048576ll, 1048576ll);

  // 4) S = Q K^T / 32 (fp32 out), batched over 4
  gemm_bt<<<dim3(16, 16, 4), dim3(256), 0, stream>>>(
      Q, Q, Kb, Kb, S, S, nullptr, 2048, 2048, 1024, 1024, 2048, 1024, 1024,
      2048, 0.03125f, 0, 0, 2048ll * 1024, 2048ll * 1024, 2048ll * 2048);

  // 5) P = softmax rows of S -> P0/P1 (over Q/K buffers)
  softmax_split<<<dim3(8192), dim3(256), 0, stream>>>(S, P0, P1);

  // 6) O = P0 VT0^T + P1 VT1^T (dual K-segment), bf16, over xb
  gemm_bt<<<dim3(8, 16, 4), dim3(256), 0, stream>>>(
      P0, P1, VT, VT + 1048576, O, O, nullptr, 2048, 1024, 2048, 1024, 1024,
      1024, 1024, 1024, 1.f, 1, 0, 2048ll * 1024, 2097152ll, 2048ll * 1024);

  // 7) out = O @ Wo^T + bo, fp32 to d_out
  gemm_bt<<<dim3(8, 64, 1), dim3(256), 0, stream>>>(
      O, O, wob, wob, out, out, bo, 8192, 1024, 1024, 1024, 1024, 1024, 1024,
      1024, 1.f, 0, 1, 0, 0, 0);
}